// Round 2
// baseline (472.158 us; speedup 1.0000x reference)
//
#include <hip/hip_runtime.h>
#include <cstdint>
#include <cstddef>

typedef __attribute__((ext_vector_type(8))) short short8;
typedef __attribute__((ext_vector_type(4))) float f32x4;
typedef unsigned short u16;

#define MFMA16(a, b, c) __builtin_amdgcn_mfma_f32_16x16x32_bf16((a), (b), (c), 0, 0, 0)

__device__ __forceinline__ u16 f2bf(float f) {
  union { float f; unsigned u; } c; c.f = f;
  unsigned r = c.u + 0x7fffu + ((c.u >> 16) & 1u);
  return (u16)(r >> 16);
}

// ---------------------------------------------------------------------------
// Weight prep kernels (run every call; stateless)
// ---------------------------------------------------------------------------

// out[n][d] (bf16, [2048][1024]) = concat(W_Q, W_K, W_V) transposed.
// W_Q: [d][n] n<1024 ; W_K/W_V: [d][n'] n'<512.
__global__ __launch_bounds__(256) void prep_wqkv(const float* __restrict__ wq,
    const float* __restrict__ wk, const float* __restrict__ wv, u16* __restrict__ outp)
{
  __shared__ float t[32][33];
  const int tx = threadIdx.x & 31, ty = threadIdx.x >> 5;
  const int n0 = blockIdx.x * 32, d0 = blockIdx.y * 32;
  const float* src; int stride, nc;
  if (n0 < 1024)      { src = wq; stride = 1024; nc = n0; }
  else if (n0 < 1536) { src = wk; stride = 512;  nc = n0 - 1024; }
  else                { src = wv; stride = 512;  nc = n0 - 1536; }
#pragma unroll
  for (int i = 0; i < 32; i += 8)
    t[ty + i][tx] = src[(size_t)(d0 + ty + i) * stride + nc + tx];
  __syncthreads();
#pragma unroll
  for (int i = 0; i < 32; i += 8)
    outp[(size_t)(n0 + ty + i) * 1024 + d0 + tx] = f2bf(t[tx][ty + i]);
}

// out[d][c] (bf16 [1024][1024]) where c = h*64+k, in = W_out[k][h][d]
__global__ __launch_bounds__(256) void prep_wout(const float* __restrict__ wo, u16* __restrict__ outp)
{
  __shared__ float t[32][33];
  const int tx = threadIdx.x & 31, ty = threadIdx.x >> 5;
  const int d0 = blockIdx.x * 32, c0 = blockIdx.y * 32;
#pragma unroll
  for (int i = 0; i < 32; i += 8) {
    int c = c0 + ty + i;
    t[ty + i][tx] = wo[(size_t)(c & 63) * 16384 + (size_t)(c >> 6) * 1024 + d0 + tx];
  }
  __syncthreads();
#pragma unroll
  for (int i = 0; i < 32; i += 8)
    outp[(size_t)(d0 + ty + i) * 1024 + c0 + tx] = f2bf(t[tx][ty + i]);
}

__global__ void convert_bf16(const float4* __restrict__ in, u16* __restrict__ out, int n4) {
  int i = blockIdx.x * 256 + threadIdx.x;
  if (i >= n4) return;
  float4 v = in[i];
  ushort4 o; o.x = f2bf(v.x); o.y = f2bf(v.y); o.z = f2bf(v.z); o.w = f2bf(v.w);
  ((ushort4*)out)[i] = o;
}

// Vt[b][g][k][t] from qkv cols 1536+g*64+k
__global__ __launch_bounds__(256) void vt_transpose(const u16* __restrict__ qkv, u16* __restrict__ vtp)
{
  __shared__ u16 t[32][33];
  const int tx = threadIdx.x & 31, ty = threadIdx.x >> 5;
  const int t0 = blockIdx.x * 32, k0 = blockIdx.y * 32;
  const int bg = blockIdx.z, b = bg >> 3, g = bg & 7;
#pragma unroll
  for (int i = 0; i < 32; i += 8)
    t[ty + i][tx] = qkv[(size_t)(b * 2048 + t0 + ty + i) * 2048 + 1536 + g * 64 + k0 + tx];
  __syncthreads();
#pragma unroll
  for (int i = 0; i < 32; i += 8)
    vtp[(size_t)(bg * 64 + k0 + ty + i) * 2048 + t0 + tx] = t[tx][ty + i];
}

// ---------------------------------------------------------------------------
// LayerNorm (fp32 in -> bf16 out), one block per row of 1024
// ---------------------------------------------------------------------------
__global__ __launch_bounds__(256) void ln_bf16(const float* __restrict__ x,
    const float* __restrict__ w, const float* __restrict__ b, u16* __restrict__ out)
{
  const int row = blockIdx.x, tid = threadIdx.x;
  const float4 v = ((const float4*)(x + (size_t)row * 1024))[tid];
  float s = v.x + v.y + v.z + v.w;
  float s2 = v.x * v.x + v.y * v.y + v.z * v.z + v.w * v.w;
#pragma unroll
  for (int m = 32; m >= 1; m >>= 1) { s += __shfl_xor(s, m); s2 += __shfl_xor(s2, m); }
  __shared__ float red[8];
  if ((tid & 63) == 0) { red[tid >> 6] = s; red[4 + (tid >> 6)] = s2; }
  __syncthreads();
  s  = red[0] + red[1] + red[2] + red[3];
  s2 = red[4] + red[5] + red[6] + red[7];
  const float mu = s * (1.f / 1024.f);
  const float inv = rsqrtf(s2 * (1.f / 1024.f) - mu * mu + 1e-5f);
  const float4 wv = ((const float4*)w)[tid];
  const float4 bv = ((const float4*)b)[tid];
  ushort4 o;
  o.x = f2bf((v.x - mu) * inv * wv.x + bv.x);
  o.y = f2bf((v.y - mu) * inv * wv.y + bv.y);
  o.z = f2bf((v.z - mu) * inv * wv.z + bv.z);
  o.w = f2bf((v.w - mu) * inv * wv.w + bv.w);
  ((ushort4*)out)[(size_t)row * 256 + tid] = o;
}

// ---------------------------------------------------------------------------
// GEMM: C[M][N] = A[M][K] * Bt[N][K]^T  (bf16 in, fp32 accum)
// 128x128 tile, BK=32, 4 waves (each 64x64), global_load_lds staging.
// EPI: 0 = store bf16 ; 1 = +bias +resid -> fp32 ; 2 = +bias, GELU -> bf16
// ---------------------------------------------------------------------------
#define BM 128
#define BN 128
#define BK 32

template<int EPI>
__global__ __launch_bounds__(256, 2) void gemm_bt(
    const u16* __restrict__ A, const u16* __restrict__ Bt, void* __restrict__ Cout,
    const float* __restrict__ bias, const float* __restrict__ resid,
    int M, int N, int K)
{
  __shared__ u16 As[BM * BK];
  __shared__ u16 Bs[BN * BK];
  const int tid = threadIdx.x;
  const int w = tid >> 6, lane = tid & 63;
  const int lo = lane & 15, hi = lane >> 4;
  const int mBase = blockIdx.x * BM, nBase = blockIdx.y * BN;
  const int wr = (w >> 1) * 64, wc = (w & 1) * 64;

  const f32x4 vzero = {0.f, 0.f, 0.f, 0.f};
  f32x4 acc[4][4];
#pragma unroll
  for (int i = 0; i < 4; ++i)
#pragma unroll
    for (int j = 0; j < 4; ++j) acc[i][j] = vzero;

  const int base0 = w * 2048 + lane * 16;   // byte offset in 8KB tile

  for (int k0 = 0; k0 < K; k0 += BK) {
    __syncthreads();
#pragma unroll
    for (int c = 0; c < 2; ++c) {
      const int off = base0 + c * 1024;
      const int row = off >> 6, kb = (off & 63) >> 1;
      const u16* ga = A  + (size_t)(mBase + row) * K + k0 + kb;
      const u16* gb = Bt + (size_t)(nBase + row) * K + k0 + kb;
      __builtin_amdgcn_global_load_lds((const __attribute__((address_space(1))) void*)ga,
          (__attribute__((address_space(3))) void*)((char*)As + w * 2048 + c * 1024), 16, 0, 0);
      __builtin_amdgcn_global_load_lds((const __attribute__((address_space(1))) void*)gb,
          (__attribute__((address_space(3))) void*)((char*)Bs + w * 2048 + c * 1024), 16, 0, 0);
    }
    __syncthreads();
    short8 af[4], bf[4];
#pragma unroll
    for (int i = 0; i < 4; ++i) {
      af[i] = *(const short8*)((const char*)As + (wr + i * 16 + lo) * 64 + hi * 16);
      bf[i] = *(const short8*)((const char*)Bs + (wc + i * 16 + lo) * 64 + hi * 16);
    }
#pragma unroll
    for (int i = 0; i < 4; ++i)
#pragma unroll
      for (int j = 0; j < 4; ++j)
        acc[i][j] = MFMA16(af[i], bf[j], acc[i][j]);
  }

#pragma unroll
  for (int i = 0; i < 4; ++i) {
#pragma unroll
    for (int j = 0; j < 4; ++j) {
#pragma unroll
      for (int r = 0; r < 4; ++r) {
        const int row = mBase + wr + i * 16 + hi * 4 + r;
        const int col = nBase + wc + j * 16 + lo;
        float v = acc[i][j][r];
        if (EPI != 0) v += bias[col];
        if (EPI == 1) v += resid[(size_t)row * N + col];
        if (EPI == 2) v = 0.5f * v * (1.f + erff(v * 0.70710678118f));
        if (EPI == 1) ((float*)Cout)[(size_t)row * N + col] = v;
        else          ((u16*)Cout)[(size_t)row * N + col] = f2bf(v);
      }
    }
  }
}

// ---------------------------------------------------------------------------
// Flash attention: one wave per 16 q-rows. QKV bf16 [4096][2048], Vt bf16.
// z out bf16 [4096][1024] (col = h*64 + k)
// ---------------------------------------------------------------------------
__global__ __launch_bounds__(256) void attn_fwd(const u16* __restrict__ qkv,
    const u16* __restrict__ vt, u16* __restrict__ z)
{
  __shared__ u16 Pl[4][16 * 64];
  const int tid = threadIdx.x;
  const int w = tid >> 6, lane = tid & 63, lo = lane & 15, hi = lane >> 4;
  const int q0 = blockIdx.x * 64 + w * 16;
  const int bh = blockIdx.y, b = bh >> 4, h = bh & 15, g = h >> 1;

  const u16* qp = qkv + (size_t)(b * 2048 + q0 + lo) * 2048 + h * 64;
  const short8 qA0 = *(const short8*)(qp + hi * 8);
  const short8 qA1 = *(const short8*)(qp + 32 + hi * 8);

  const f32x4 vzero = {0.f, 0.f, 0.f, 0.f};
  f32x4 zacc[4];
#pragma unroll
  for (int nt = 0; nt < 4; ++nt) zacc[nt] = vzero;
  float mrun[4] = {-1e30f, -1e30f, -1e30f, -1e30f};
  float lrun[4] = {0.f, 0.f, 0.f, 0.f};

  const int tEnd = q0 + 16;
  for (int t0 = 0; t0 < tEnd; t0 += 64) {
    const u16* kb = qkv + (size_t)(b * 2048 + t0 + lo) * 2048 + 1024 + g * 64;
    const bool needMask = (t0 + 63 > q0);
    float p[4][4];
#pragma unroll
    for (int nt = 0; nt < 4; ++nt) {
      f32x4 sv = vzero;
      const u16* kr = kb + (size_t)nt * 16 * 2048;
      sv = MFMA16(qA0, *(const short8*)(kr + hi * 8), sv);
      sv = MFMA16(qA1, *(const short8*)(kr + 32 + hi * 8), sv);
#pragma unroll
      for (int r = 0; r < 4; ++r) {
        float val = sv[r] * 0.125f;
        if (needMask && (t0 + nt * 16 + lo > q0 + hi * 4 + r)) val = -1e30f;
        p[nt][r] = val;
      }
    }
#pragma unroll
    for (int r = 0; r < 4; ++r) {
      float mx = fmaxf(fmaxf(p[0][r], p[1][r]), fmaxf(p[2][r], p[3][r]));
      mx = fmaxf(mx, __shfl_xor(mx, 1));
      mx = fmaxf(mx, __shfl_xor(mx, 2));
      mx = fmaxf(mx, __shfl_xor(mx, 4));
      mx = fmaxf(mx, __shfl_xor(mx, 8));
      const float nm = fmaxf(mrun[r], mx);
      const float sc = __expf(mrun[r] - nm);
      float rs = 0.f;
#pragma unroll
      for (int nt = 0; nt < 4; ++nt) { p[nt][r] = __expf(p[nt][r] - nm); rs += p[nt][r]; }
      rs += __shfl_xor(rs, 1); rs += __shfl_xor(rs, 2);
      rs += __shfl_xor(rs, 4); rs += __shfl_xor(rs, 8);
      lrun[r] = lrun[r] * sc + rs;
      mrun[r] = nm;
      zacc[0][r] *= sc; zacc[1][r] *= sc; zacc[2][r] *= sc; zacc[3][r] *= sc;
    }
    u16* pw = &Pl[w][0];
#pragma unroll
    for (int nt = 0; nt < 4; ++nt)
#pragma unroll
      for (int r = 0; r < 4; ++r)
        pw[(hi * 4 + r) * 64 + nt * 16 + lo] = f2bf(p[nt][r]);
    asm volatile("s_waitcnt lgkmcnt(0)" ::: "memory");
    const short8 pf0 = *(const short8*)(pw + lo * 64 + hi * 8);
    const short8 pf1 = *(const short8*)(pw + lo * 64 + 32 + hi * 8);
    const u16* vb = vt + ((size_t)(b * 8 + g) * 64) * 2048 + t0;
#pragma unroll
    for (int nt = 0; nt < 4; ++nt) {
      const u16* vr = vb + (size_t)(nt * 16 + lo) * 2048;
      zacc[nt] = MFMA16(pf0, *(const short8*)(vr + hi * 8), zacc[nt]);
      zacc[nt] = MFMA16(pf1, *(const short8*)(vr + 32 + hi * 8), zacc[nt]);
    }
  }

  u16* zp = z + (size_t)(b * 2048 + q0) * 1024 + h * 64;
#pragma unroll
  for (int r = 0; r < 4; ++r) {
    const float inv = 1.f / lrun[r];
#pragma unroll
    for (int nt = 0; nt < 4; ++nt)
      zp[(size_t)(hi * 4 + r) * 1024 + nt * 16 + lo] = f2bf(zacc[nt][r] * inv);
  }
}

// ---------------------------------------------------------------------------

extern "C" void kernel_launch(void* const* d_in, const int* in_sizes, int n_in,
                              void* d_out, int out_size, void* d_ws, size_t ws_size,
                              hipStream_t stream)
{
  (void)in_sizes; (void)n_in; (void)out_size; (void)ws_size;
  const float* x      = (const float*)d_in[0];
  const float* ln1_w  = (const float*)d_in[1];
  const float* ln1_b  = (const float*)d_in[2];
  const float* W_Q    = (const float*)d_in[3];
  const float* W_K    = (const float*)d_in[4];
  const float* W_V    = (const float*)d_in[5];
  const float* W_out  = (const float*)d_in[6];
  const float* b_out  = (const float*)d_in[7];
  const float* ln2_w  = (const float*)d_in[8];
  const float* ln2_b  = (const float*)d_in[9];
  const float* mlp1_w = (const float*)d_in[10];
  const float* mlp1_b = (const float*)d_in[11];
  const float* mlp2_w = (const float*)d_in[12];
  const float* mlp2_b = (const float*)d_in[13];
  float* out = (float*)d_out;

  char* ws = (char*)d_ws;
  u16*   wqkv_t = (u16*)(ws + 0);           // [2048][1024] bf16   4 MB
  u16*   wout_t = (u16*)(ws + 4194304);     // [1024][1024] bf16   2 MB
  u16*   w1     = (u16*)(ws + 6291456);     // [4096][1024] bf16   8 MB
  u16*   w2     = (u16*)(ws + 14680064);    // [1024][4096] bf16   8 MB
  u16*   normed = (u16*)(ws + 23068672);    // [4096][1024] bf16   8 MB (reused for ln2)
  float* post   = (float*)(ws + 31457280);  // [4096][1024] f32   16 MB
  u16*   qkv    = (u16*)(ws + 48234496);    // [4096][2048] bf16  16 MB
  u16*   vtb    = (u16*)(ws + 65011712);    // [16][64][2048] bf16 4 MB
  u16*   zb     = (u16*)(ws + 69206016);    // [4096][1024] bf16   8 MB
  u16*   hbuf   = (u16*)(ws + 48234496);    // [4096][4096] bf16  32 MB (reuses qkv/vt/z)

  prep_wqkv<<<dim3(64, 32), 256, 0, stream>>>(W_Q, W_K, W_V, wqkv_t);
  prep_wout<<<dim3(32, 32), 256, 0, stream>>>(W_out, wout_t);
  convert_bf16<<<4096, 256, 0, stream>>>((const float4*)mlp1_w, w1, 1048576);
  convert_bf16<<<4096, 256, 0, stream>>>((const float4*)mlp2_w, w2, 1048576);

  ln_bf16<<<4096, 256, 0, stream>>>(x, ln1_w, ln1_b, normed);
  gemm_bt<0><<<dim3(32, 16), 256, 0, stream>>>(normed, wqkv_t, qkv, nullptr, nullptr, 4096, 2048, 1024);
  vt_transpose<<<dim3(64, 2, 16), 256, 0, stream>>>(qkv, vtb);
  attn_fwd<<<dim3(32, 32), 256, 0, stream>>>(qkv, vtb, zb);
  gemm_bt<1><<<dim3(32, 8), 256, 0, stream>>>(zb, wout_t, post, b_out, x, 4096, 1024, 1024);
  ln_bf16<<<4096, 256, 0, stream>>>(post, ln2_w, ln2_b, normed);
  gemm_bt<2><<<dim3(32, 32), 256, 0, stream>>>(normed, w1, hbuf, mlp1_b, nullptr, 4096, 4096, 1024);
  gemm_bt<1><<<dim3(32, 8), 256, 0, stream>>>(hbuf, w2, out, mlp2_b, post, 4096, 1024, 4096);
}

// Round 3
// 325.932 us; speedup vs baseline: 1.4486x; 1.4486x over previous
//
#include <hip/hip_runtime.h>
#include <cstdint>
#include <cstddef>

typedef __attribute__((ext_vector_type(8))) short short8;
typedef __attribute__((ext_vector_type(4))) float f32x4;
typedef unsigned short u16;

#define MFMA16(a, b, c) __builtin_amdgcn_mfma_f32_16x16x32_bf16((a), (b), (c), 0, 0, 0)

__device__ __forceinline__ u16 f2bf(float f) {
  union { float f; unsigned u; } c; c.f = f;
  unsigned r = c.u + 0x7fffu + ((c.u >> 16) & 1u);
  return (u16)(r >> 16);
}

// ---------------------------------------------------------------------------
// Weight prep kernels (run every call; stateless)
// ---------------------------------------------------------------------------

__global__ __launch_bounds__(256) void prep_wqkv(const float* __restrict__ wq,
    const float* __restrict__ wk, const float* __restrict__ wv, u16* __restrict__ outp)
{
  __shared__ float t[32][33];
  const int tx = threadIdx.x & 31, ty = threadIdx.x >> 5;
  const int n0 = blockIdx.x * 32, d0 = blockIdx.y * 32;
  const float* src; int stride, nc;
  if (n0 < 1024)      { src = wq; stride = 1024; nc = n0; }
  else if (n0 < 1536) { src = wk; stride = 512;  nc = n0 - 1024; }
  else                { src = wv; stride = 512;  nc = n0 - 1536; }
#pragma unroll
  for (int i = 0; i < 32; i += 8)
    t[ty + i][tx] = src[(size_t)(d0 + ty + i) * stride + nc + tx];
  __syncthreads();
#pragma unroll
  for (int i = 0; i < 32; i += 8)
    outp[(size_t)(n0 + ty + i) * 1024 + d0 + tx] = f2bf(t[tx][ty + i]);
}

__global__ __launch_bounds__(256) void prep_wout(const float* __restrict__ wo, u16* __restrict__ outp)
{
  __shared__ float t[32][33];
  const int tx = threadIdx.x & 31, ty = threadIdx.x >> 5;
  const int d0 = blockIdx.x * 32, c0 = blockIdx.y * 32;
#pragma unroll
  for (int i = 0; i < 32; i += 8) {
    int c = c0 + ty + i;
    t[ty + i][tx] = wo[(size_t)(c & 63) * 16384 + (size_t)(c >> 6) * 1024 + d0 + tx];
  }
  __syncthreads();
#pragma unroll
  for (int i = 0; i < 32; i += 8)
    outp[(size_t)(d0 + ty + i) * 1024 + c0 + tx] = f2bf(t[tx][ty + i]);
}

__global__ void convert_bf16(const float4* __restrict__ in, u16* __restrict__ out, int n4) {
  int i = blockIdx.x * 256 + threadIdx.x;
  if (i >= n4) return;
  float4 v = in[i];
  ushort4 o; o.x = f2bf(v.x); o.y = f2bf(v.y); o.z = f2bf(v.z); o.w = f2bf(v.w);
  ((ushort4*)out)[i] = o;
}

// Vt[b][g][k][t] from qkv cols 1536+g*64+k
__global__ __launch_bounds__(256) void vt_transpose(const u16* __restrict__ qkv, u16* __restrict__ vtp)
{
  __shared__ u16 t[32][33];
  const int tx = threadIdx.x & 31, ty = threadIdx.x >> 5;
  const int t0 = blockIdx.x * 32, k0 = blockIdx.y * 32;
  const int bg = blockIdx.z, b = bg >> 3, g = bg & 7;
#pragma unroll
  for (int i = 0; i < 32; i += 8)
    t[ty + i][tx] = qkv[(size_t)(b * 2048 + t0 + ty + i) * 2048 + 1536 + g * 64 + k0 + tx];
  __syncthreads();
#pragma unroll
  for (int i = 0; i < 32; i += 8)
    vtp[(size_t)(bg * 64 + k0 + ty + i) * 2048 + t0 + tx] = t[tx][ty + i];
}

// ---------------------------------------------------------------------------
// LayerNorm (fp32 in -> bf16 out)
// ---------------------------------------------------------------------------
__global__ __launch_bounds__(256) void ln_bf16(const float* __restrict__ x,
    const float* __restrict__ w, const float* __restrict__ b, u16* __restrict__ out)
{
  const int row = blockIdx.x, tid = threadIdx.x;
  const float4 v = ((const float4*)(x + (size_t)row * 1024))[tid];
  float s = v.x + v.y + v.z + v.w;
  float s2 = v.x * v.x + v.y * v.y + v.z * v.z + v.w * v.w;
#pragma unroll
  for (int m = 32; m >= 1; m >>= 1) { s += __shfl_xor(s, m); s2 += __shfl_xor(s2, m); }
  __shared__ float red[8];
  if ((tid & 63) == 0) { red[tid >> 6] = s; red[4 + (tid >> 6)] = s2; }
  __syncthreads();
  s  = red[0] + red[1] + red[2] + red[3];
  s2 = red[4] + red[5] + red[6] + red[7];
  const float mu = s * (1.f / 1024.f);
  const float inv = rsqrtf(s2 * (1.f / 1024.f) - mu * mu + 1e-5f);
  const float4 wv = ((const float4*)w)[tid];
  const float4 bv = ((const float4*)b)[tid];
  ushort4 o;
  o.x = f2bf((v.x - mu) * inv * wv.x + bv.x);
  o.y = f2bf((v.y - mu) * inv * wv.y + bv.y);
  o.z = f2bf((v.z - mu) * inv * wv.z + bv.z);
  o.w = f2bf((v.w - mu) * inv * wv.w + bv.w);
  ((ushort4*)out)[(size_t)row * 256 + tid] = o;
}

// ---------------------------------------------------------------------------
// GEMM: C[M][N] = A[M][K] * Bt[N][K]^T  (bf16 in, fp32 accum) — unchanged
// ---------------------------------------------------------------------------
#define BM 128
#define BN 128
#define BK 32

template<int EPI>
__global__ __launch_bounds__(256, 2) void gemm_bt(
    const u16* __restrict__ A, const u16* __restrict__ Bt, void* __restrict__ Cout,
    const float* __restrict__ bias, const float* __restrict__ resid,
    int M, int N, int K)
{
  __shared__ u16 As[BM * BK];
  __shared__ u16 Bs[BN * BK];
  const int tid = threadIdx.x;
  const int w = tid >> 6, lane = tid & 63;
  const int lo = lane & 15, hi = lane >> 4;
  const int mBase = blockIdx.x * BM, nBase = blockIdx.y * BN;
  const int wr = (w >> 1) * 64, wc = (w & 1) * 64;

  const f32x4 vzero = {0.f, 0.f, 0.f, 0.f};
  f32x4 acc[4][4];
#pragma unroll
  for (int i = 0; i < 4; ++i)
#pragma unroll
    for (int j = 0; j < 4; ++j) acc[i][j] = vzero;

  const int base0 = w * 2048 + lane * 16;

  for (int k0 = 0; k0 < K; k0 += BK) {
    __syncthreads();
#pragma unroll
    for (int c = 0; c < 2; ++c) {
      const int off = base0 + c * 1024;
      const int row = off >> 6, kb = (off & 63) >> 1;
      const u16* ga = A  + (size_t)(mBase + row) * K + k0 + kb;
      const u16* gb = Bt + (size_t)(nBase + row) * K + k0 + kb;
      __builtin_amdgcn_global_load_lds((const __attribute__((address_space(1))) void*)ga,
          (__attribute__((address_space(3))) void*)((char*)As + w * 2048 + c * 1024), 16, 0, 0);
      __builtin_amdgcn_global_load_lds((const __attribute__((address_space(1))) void*)gb,
          (__attribute__((address_space(3))) void*)((char*)Bs + w * 2048 + c * 1024), 16, 0, 0);
    }
    __syncthreads();
    short8 af[4], bf[4];
#pragma unroll
    for (int i = 0; i < 4; ++i) {
      af[i] = *(const short8*)((const char*)As + (wr + i * 16 + lo) * 64 + hi * 16);
      bf[i] = *(const short8*)((const char*)Bs + (wc + i * 16 + lo) * 64 + hi * 16);
    }
#pragma unroll
    for (int i = 0; i < 4; ++i)
#pragma unroll
      for (int j = 0; j < 4; ++j)
        acc[i][j] = MFMA16(af[i], bf[j], acc[i][j]);
  }

#pragma unroll
  for (int i = 0; i < 4; ++i) {
#pragma unroll
    for (int j = 0; j < 4; ++j) {
#pragma unroll
      for (int r = 0; r < 4; ++r) {
        const int row = mBase + wr + i * 16 + hi * 4 + r;
        const int col = nBase + wc + j * 16 + lo;
        float v = acc[i][j][r];
        if (EPI != 0) v += bias[col];
        if (EPI == 1) v += resid[(size_t)row * N + col];
        if (EPI == 2) v = 0.5f * v * (1.f + erff(v * 0.70710678118f));
        if (EPI == 1) ((float*)Cout)[(size_t)row * N + col] = v;
        else          ((u16*)Cout)[(size_t)row * N + col] = f2bf(v);
      }
    }
  }
}

// ---------------------------------------------------------------------------
// Flash attention v2: block = 4 waves x 32 q-rows = 128 q-rows of one (b,h).
// K/V tiles (64x64 bf16) staged in LDS via global_load_lds with XOR swizzle
// (linear LDS dest + inverse-swizzled global source; swizzle applied on read).
// ---------------------------------------------------------------------------
__global__ __launch_bounds__(256) void attn_fwd(const u16* __restrict__ qkv,
    const u16* __restrict__ vt, u16* __restrict__ z)
{
  __shared__ u16 Ks[64 * 64];        // [t][d], swizzled
  __shared__ u16 Vs[64 * 64];        // [k][t], swizzled (from Vt)
  __shared__ u16 Pl[4][32 * 72];     // per-wave P exchange, padded stride 72
  const int tid = threadIdx.x;
  const int w = tid >> 6, lane = tid & 63, lo = lane & 15, hi = lane >> 4;
  const int bxr = blockIdx.x;
  const int chunk = (bxr & 1) ? (15 - (bxr >> 1)) : (bxr >> 1);   // 0,15,1,14,...
  const int bh = blockIdx.y, b = bh >> 4, h = bh & 15, g = h >> 1;
  const int q0w = chunk * 128 + w * 32;

  // Q fragments: qA[qf][half], rows q0w+qf*16+lo, d = half*32 + hi*8
  short8 qA[2][2];
#pragma unroll
  for (int qf = 0; qf < 2; ++qf)
#pragma unroll
    for (int half = 0; half < 2; ++half)
      qA[qf][half] = *(const short8*)(qkv +
          (size_t)(b * 2048 + q0w + qf * 16 + lo) * 2048 + h * 64 + half * 32 + hi * 8);

  const f32x4 vzero = {0.f, 0.f, 0.f, 0.f};
  f32x4 zacc[2][4];
#pragma unroll
  for (int qf = 0; qf < 2; ++qf)
#pragma unroll
    for (int kf = 0; kf < 4; ++kf) zacc[qf][kf] = vzero;
  float mrun[2][4], lrun[2][4];
#pragma unroll
  for (int qf = 0; qf < 2; ++qf)
#pragma unroll
    for (int r = 0; r < 4; ++r) { mrun[qf][r] = -1e30f; lrun[qf][r] = 0.f; }

  const u16* kbase = qkv + (size_t)b * 2048 * 2048 + 1024 + g * 64;
  const u16* vbase = vt + (size_t)(b * 8 + g) * 64 * 2048;

  // staging: linear LDS byte offset p -> (row, swizzled col) in global
  const int p0 = w * 2048 + lane * 16;
  int srow[2], scol[2];
#pragma unroll
  for (int c = 0; c < 2; ++c) {
    const int p = p0 + c * 1024;
    const int r = p >> 7, bb = p & 127;
    srow[c] = r;
    scol[c] = (bb ^ ((r & 7) << 4)) >> 1;
  }

  const int nTiles = (chunk + 1) * 2;
  u16* pw = &Pl[w][0];

  for (int it = 0; it < nTiles; ++it) {
    const int t0 = it * 64;
    __syncthreads();   // previous tile's LDS reads complete
#pragma unroll
    for (int c = 0; c < 2; ++c) {
      __builtin_amdgcn_global_load_lds(
          (const __attribute__((address_space(1))) void*)(kbase + (size_t)(t0 + srow[c]) * 2048 + scol[c]),
          (__attribute__((address_space(3))) void*)((char*)Ks + p0 + c * 1024), 16, 0, 0);
      __builtin_amdgcn_global_load_lds(
          (const __attribute__((address_space(1))) void*)(vbase + (size_t)srow[c] * 2048 + t0 + scol[c]),
          (__attribute__((address_space(3))) void*)((char*)Vs + p0 + c * 1024), 16, 0, 0);
    }
    __syncthreads();   // staging visible

    if (t0 < q0w + 32) {
#pragma unroll
      for (int qf = 0; qf < 2; ++qf) {
        const int qrow0 = q0w + qf * 16;
        const bool needMask = (t0 + 63 > qrow0);
        f32x4 sv[4];
#pragma unroll
        for (int nt = 0; nt < 4; ++nt) {
          const int r = nt * 16 + lo;
          const int swz = (r & 7) << 4;
          const short8 k0 = *(const short8*)((const char*)Ks + r * 128 + ((hi * 16) ^ swz));
          const short8 k1 = *(const short8*)((const char*)Ks + r * 128 + ((64 + hi * 16) ^ swz));
          f32x4 t = vzero;
          t = MFMA16(qA[qf][0], k0, t);
          t = MFMA16(qA[qf][1], k1, t);
          sv[nt] = t;
        }
#pragma unroll
        for (int r = 0; r < 4; ++r) {
          float p4[4];
#pragma unroll
          for (int nt = 0; nt < 4; ++nt) {
            float val = sv[nt][r] * 0.125f;
            if (needMask && (t0 + nt * 16 + lo > qrow0 + hi * 4 + r)) val = -1e30f;
            p4[nt] = val;
          }
          float mx = fmaxf(fmaxf(p4[0], p4[1]), fmaxf(p4[2], p4[3]));
          mx = fmaxf(mx, __shfl_xor(mx, 1));
          mx = fmaxf(mx, __shfl_xor(mx, 2));
          mx = fmaxf(mx, __shfl_xor(mx, 4));
          mx = fmaxf(mx, __shfl_xor(mx, 8));
          const float nm = fmaxf(mrun[qf][r], mx);
          const float sc = __expf(mrun[qf][r] - nm);
          float rs = 0.f;
#pragma unroll
          for (int nt = 0; nt < 4; ++nt) { p4[nt] = __expf(p4[nt] - nm); rs += p4[nt]; }
          rs += __shfl_xor(rs, 1); rs += __shfl_xor(rs, 2);
          rs += __shfl_xor(rs, 4); rs += __shfl_xor(rs, 8);
          lrun[qf][r] = lrun[qf][r] * sc + rs;
          mrun[qf][r] = nm;
#pragma unroll
          for (int kf = 0; kf < 4; ++kf) zacc[qf][kf][r] *= sc;
#pragma unroll
          for (int nt = 0; nt < 4; ++nt)
            pw[(qf * 16 + hi * 4 + r) * 72 + nt * 16 + lo] = f2bf(p4[nt]);
        }
      }
      asm volatile("s_waitcnt lgkmcnt(0)" ::: "memory");
      short8 pa[2][2];
#pragma unroll
      for (int qf = 0; qf < 2; ++qf)
#pragma unroll
        for (int tc = 0; tc < 2; ++tc)
          pa[qf][tc] = *(const short8*)(pw + (qf * 16 + lo) * 72 + tc * 32 + hi * 8);
#pragma unroll
      for (int kf = 0; kf < 4; ++kf) {
        const int r = kf * 16 + lo;
        const int swz = (r & 7) << 4;
#pragma unroll
        for (int tc = 0; tc < 2; ++tc) {
          const short8 vf = *(const short8*)((const char*)Vs + r * 128 + ((tc * 64 + hi * 16) ^ swz));
          zacc[0][kf] = MFMA16(pa[0][tc], vf, zacc[0][kf]);
          zacc[1][kf] = MFMA16(pa[1][tc], vf, zacc[1][kf]);
        }
      }
    }
  }

  u16* zp = z + (size_t)(b * 2048 + q0w) * 1024 + h * 64;
#pragma unroll
  for (int qf = 0; qf < 2; ++qf) {
#pragma unroll
    for (int r = 0; r < 4; ++r) {
      const float inv = 1.f / lrun[qf][r];
#pragma unroll
      for (int kf = 0; kf < 4; ++kf)
        zp[(size_t)(qf * 16 + hi * 4 + r) * 1024 + kf * 16 + lo] = f2bf(zacc[qf][kf][r] * inv);
    }
  }
}

// ---------------------------------------------------------------------------

extern "C" void kernel_launch(void* const* d_in, const int* in_sizes, int n_in,
                              void* d_out, int out_size, void* d_ws, size_t ws_size,
                              hipStream_t stream)
{
  (void)in_sizes; (void)n_in; (void)out_size; (void)ws_size;
  const float* x      = (const float*)d_in[0];
  const float* ln1_w  = (const float*)d_in[1];
  const float* ln1_b  = (const float*)d_in[2];
  const float* W_Q    = (const float*)d_in[3];
  const float* W_K    = (const float*)d_in[4];
  const float* W_V    = (const float*)d_in[5];
  const float* W_out  = (const float*)d_in[6];
  const float* b_out  = (const float*)d_in[7];
  const float* ln2_w  = (const float*)d_in[8];
  const float* ln2_b  = (const float*)d_in[9];
  const float* mlp1_w = (const float*)d_in[10];
  const float* mlp1_b = (const float*)d_in[11];
  const float* mlp2_w = (const float*)d_in[12];
  const float* mlp2_b = (const float*)d_in[13];
  float* out = (float*)d_out;

  char* ws = (char*)d_ws;
  u16*   wqkv_t = (u16*)(ws + 0);           // [2048][1024] bf16   4 MB
  u16*   wout_t = (u16*)(ws + 4194304);     // [1024][1024] bf16   2 MB
  u16*   w1     = (u16*)(ws + 6291456);     // [4096][1024] bf16   8 MB
  u16*   w2     = (u16*)(ws + 14680064);    // [1024][4096] bf16   8 MB
  u16*   normed = (u16*)(ws + 23068672);    // [4096][1024] bf16   8 MB
  float* post   = (float*)(ws + 31457280);  // [4096][1024] f32   16 MB
  u16*   qkv    = (u16*)(ws + 48234496);    // [4096][2048] bf16  16 MB
  u16*   vtb    = (u16*)(ws + 65011712);    // [16][64][2048] bf16 4 MB
  u16*   zb     = (u16*)(ws + 69206016);    // [4096][1024] bf16   8 MB
  u16*   hbuf   = (u16*)(ws + 48234496);    // [4096][4096] bf16  32 MB (reuses qkv/vt/z)

  prep_wqkv<<<dim3(64, 32), 256, 0, stream>>>(W_Q, W_K, W_V, wqkv_t);
  prep_wout<<<dim3(32, 32), 256, 0, stream>>>(W_out, wout_t);
  convert_bf16<<<4096, 256, 0, stream>>>((const float4*)mlp1_w, w1, 1048576);
  convert_bf16<<<4096, 256, 0, stream>>>((const float4*)mlp2_w, w2, 1048576);

  ln_bf16<<<4096, 256, 0, stream>>>(x, ln1_w, ln1_b, normed);
  gemm_bt<0><<<dim3(32, 16), 256, 0, stream>>>(normed, wqkv_t, qkv, nullptr, nullptr, 4096, 2048, 1024);
  vt_transpose<<<dim3(64, 2, 16), 256, 0, stream>>>(qkv, vtb);
  attn_fwd<<<dim3(16, 32), 256, 0, stream>>>(qkv, vtb, zb);
  gemm_bt<1><<<dim3(32, 8), 256, 0, stream>>>(zb, wout_t, post, b_out, x, 4096, 1024, 1024);
  ln_bf16<<<4096, 256, 0, stream>>>(post, ln2_w, ln2_b, normed);
  gemm_bt<2><<<dim3(32, 32), 256, 0, stream>>>(normed, w1, hbuf, mlp1_b, nullptr, 4096, 4096, 1024);
  gemm_bt<1><<<dim3(32, 8), 256, 0, stream>>>(hbuf, w2, out, mlp2_b, post, 4096, 1024, 4096);
}

// Round 5
// 311.691 us; speedup vs baseline: 1.5148x; 1.0457x over previous
//
#include <hip/hip_runtime.h>
#include <cstdint>
#include <cstddef>

typedef __attribute__((ext_vector_type(8))) short short8;
typedef __attribute__((ext_vector_type(4))) float f32x4;
typedef unsigned short u16;

#define MFMA16(a, b, c) __builtin_amdgcn_mfma_f32_16x16x32_bf16((a), (b), (c), 0, 0, 0)

__device__ __forceinline__ u16 f2bf(float f) {
  union { float f; unsigned u; } c; c.f = f;
  unsigned r = c.u + 0x7fffu + ((c.u >> 16) & 1u);
  return (u16)(r >> 16);
}

// ---------------------------------------------------------------------------
// Weight prep kernels (run every call; stateless)
// ---------------------------------------------------------------------------

__global__ __launch_bounds__(256) void prep_wqkv(const float* __restrict__ wq,
    const float* __restrict__ wk, const float* __restrict__ wv, u16* __restrict__ outp)
{
  __shared__ float t[32][33];
  const int tx = threadIdx.x & 31, ty = threadIdx.x >> 5;
  const int n0 = blockIdx.x * 32, d0 = blockIdx.y * 32;
  const float* src; int stride, nc;
  if (n0 < 1024)      { src = wq; stride = 1024; nc = n0; }
  else if (n0 < 1536) { src = wk; stride = 512;  nc = n0 - 1024; }
  else                { src = wv; stride = 512;  nc = n0 - 1536; }
#pragma unroll
  for (int i = 0; i < 32; i += 8)
    t[ty + i][tx] = src[(size_t)(d0 + ty + i) * stride + nc + tx];
  __syncthreads();
#pragma unroll
  for (int i = 0; i < 32; i += 8)
    outp[(size_t)(n0 + ty + i) * 1024 + d0 + tx] = f2bf(t[tx][ty + i]);
}

__global__ __launch_bounds__(256) void prep_wout(const float* __restrict__ wo, u16* __restrict__ outp)
{
  __shared__ float t[32][33];
  const int tx = threadIdx.x & 31, ty = threadIdx.x >> 5;
  const int d0 = blockIdx.x * 32, c0 = blockIdx.y * 32;
#pragma unroll
  for (int i = 0; i < 32; i += 8) {
    int c = c0 + ty + i;
    t[ty + i][tx] = wo[(size_t)(c & 63) * 16384 + (size_t)(c >> 6) * 1024 + d0 + tx];
  }
  __syncthreads();
#pragma unroll
  for (int i = 0; i < 32; i += 8)
    outp[(size_t)(d0 + ty + i) * 1024 + c0 + tx] = f2bf(t[tx][ty + i]);
}

__global__ void convert_bf16(const float4* __restrict__ in, u16* __restrict__ out, int n4) {
  int i = blockIdx.x * 256 + threadIdx.x;
  if (i >= n4) return;
  float4 v = in[i];
  ushort4 o; o.x = f2bf(v.x); o.y = f2bf(v.y); o.z = f2bf(v.z); o.w = f2bf(v.w);
  ((ushort4*)out)[i] = o;
}

// Vt[b][g][k][t] from qkv cols 1536+g*64+k
__global__ __launch_bounds__(256) void vt_transpose(const u16* __restrict__ qkv, u16* __restrict__ vtp)
{
  __shared__ u16 t[32][33];
  const int tx = threadIdx.x & 31, ty = threadIdx.x >> 5;
  const int t0 = blockIdx.x * 32, k0 = blockIdx.y * 32;
  const int bg = blockIdx.z, b = bg >> 3, g = bg & 7;
#pragma unroll
  for (int i = 0; i < 32; i += 8)
    t[ty + i][tx] = qkv[(size_t)(b * 2048 + t0 + ty + i) * 2048 + 1536 + g * 64 + k0 + tx];
  __syncthreads();
#pragma unroll
  for (int i = 0; i < 32; i += 8)
    vtp[(size_t)(bg * 64 + k0 + ty + i) * 2048 + t0 + tx] = t[tx][ty + i];
}

// ---------------------------------------------------------------------------
// LayerNorm (fp32 in -> bf16 out)
// ---------------------------------------------------------------------------
__global__ __launch_bounds__(256) void ln_bf16(const float* __restrict__ x,
    const float* __restrict__ w, const float* __restrict__ b, u16* __restrict__ out)
{
  const int row = blockIdx.x, tid = threadIdx.x;
  const float4 v = ((const float4*)(x + (size_t)row * 1024))[tid];
  float s = v.x + v.y + v.z + v.w;
  float s2 = v.x * v.x + v.y * v.y + v.z * v.z + v.w * v.w;
#pragma unroll
  for (int m = 32; m >= 1; m >>= 1) { s += __shfl_xor(s, m); s2 += __shfl_xor(s2, m); }
  __shared__ float red[8];
  if ((tid & 63) == 0) { red[tid >> 6] = s; red[4 + (tid >> 6)] = s2; }
  __syncthreads();
  s  = red[0] + red[1] + red[2] + red[3];
  s2 = red[4] + red[5] + red[6] + red[7];
  const float mu = s * (1.f / 1024.f);
  const float inv = rsqrtf(s2 * (1.f / 1024.f) - mu * mu + 1e-5f);
  const float4 wv = ((const float4*)w)[tid];
  const float4 bv = ((const float4*)b)[tid];
  ushort4 o;
  o.x = f2bf((v.x - mu) * inv * wv.x + bv.x);
  o.y = f2bf((v.y - mu) * inv * wv.y + bv.y);
  o.z = f2bf((v.z - mu) * inv * wv.z + bv.z);
  o.w = f2bf((v.w - mu) * inv * wv.w + bv.w);
  ((ushort4*)out)[(size_t)row * 256 + tid] = o;
}

// ---------------------------------------------------------------------------
// GEMM: C[M][N] = A[M][K] * Bt[N][K]^T  (bf16 in, fp32 accum) — unchanged
// ---------------------------------------------------------------------------
#define BM 128
#define BN 128
#define BK 32

template<int EPI>
__global__ __launch_bounds__(256, 2) void gemm_bt(
    const u16* __restrict__ A, const u16* __restrict__ Bt, void* __restrict__ Cout,
    const float* __restrict__ bias, const float* __restrict__ resid,
    int M, int N, int K)
{
  __shared__ u16 As[BM * BK];
  __shared__ u16 Bs[BN * BK];
  const int tid = threadIdx.x;
  const int w = tid >> 6, lane = tid & 63;
  const int lo = lane & 15, hi = lane >> 4;
  const int mBase = blockIdx.x * BM, nBase = blockIdx.y * BN;
  const int wr = (w >> 1) * 64, wc = (w & 1) * 64;

  const f32x4 vzero = {0.f, 0.f, 0.f, 0.f};
  f32x4 acc[4][4];
#pragma unroll
  for (int i = 0; i < 4; ++i)
#pragma unroll
    for (int j = 0; j < 4; ++j) acc[i][j] = vzero;

  const int base0 = w * 2048 + lane * 16;

  for (int k0 = 0; k0 < K; k0 += BK) {
    __syncthreads();
#pragma unroll
    for (int c = 0; c < 2; ++c) {
      const int off = base0 + c * 1024;
      const int row = off >> 6, kb = (off & 63) >> 1;
      const u16* ga = A  + (size_t)(mBase + row) * K + k0 + kb;
      const u16* gb = Bt + (size_t)(nBase + row) * K + k0 + kb;
      __builtin_amdgcn_global_load_lds((const __attribute__((address_space(1))) void*)ga,
          (__attribute__((address_space(3))) void*)((char*)As + w * 2048 + c * 1024), 16, 0, 0);
      __builtin_amdgcn_global_load_lds((const __attribute__((address_space(1))) void*)gb,
          (__attribute__((address_space(3))) void*)((char*)Bs + w * 2048 + c * 1024), 16, 0, 0);
    }
    __syncthreads();
    short8 af[4], bf[4];
#pragma unroll
    for (int i = 0; i < 4; ++i) {
      af[i] = *(const short8*)((const char*)As + (wr + i * 16 + lo) * 64 + hi * 16);
      bf[i] = *(const short8*)((const char*)Bs + (wc + i * 16 + lo) * 64 + hi * 16);
    }
#pragma unroll
    for (int i = 0; i < 4; ++i)
#pragma unroll
      for (int j = 0; j < 4; ++j)
        acc[i][j] = MFMA16(af[i], bf[j], acc[i][j]);
  }

#pragma unroll
  for (int i = 0; i < 4; ++i) {
#pragma unroll
    for (int j = 0; j < 4; ++j) {
#pragma unroll
      for (int r = 0; r < 4; ++r) {
        const int row = mBase + wr + i * 16 + hi * 4 + r;
        const int col = nBase + wc + j * 16 + lo;
        float v = acc[i][j][r];
        if (EPI != 0) v += bias[col];
        if (EPI == 1) v += resid[(size_t)row * N + col];
        if (EPI == 2) v = 0.5f * v * (1.f + erff(v * 0.70710678118f));
        if (EPI == 1) ((float*)Cout)[(size_t)row * N + col] = v;
        else          ((u16*)Cout)[(size_t)row * N + col] = f2bf(v);
      }
    }
  }
}

// ---------------------------------------------------------------------------
// Flash attention v3-lite: swapped QK^T (S^T via MFMA(K,Q)) -> in-lane softmax
// over t (2 shfl steps), swapped PV -> lane-local rescale. Staging structure
// identical to the verified round-3 kernel (single buffer, 2 barriers/tile).
// P pack via known-good f2bf bit-round (no inline-asm cvt).
// ---------------------------------------------------------------------------
#define SCL2 0.18033688011112042f   /* 0.125 * log2(e) */

__global__ __launch_bounds__(256) void attn_fwd(const u16* __restrict__ qkv,
    const u16* __restrict__ vt, u16* __restrict__ z)
{
  __shared__ u16 Ks[64 * 64];        // [t][d], swizzled cols
  __shared__ u16 Vs[64 * 64];        // [k][t], swizzled cols
  __shared__ u16 Pl[4][32 * 72];     // per-wave P[q][t], stride 72 u16
  const int tid = threadIdx.x;
  const int w = tid >> 6, lane = tid & 63, lo = lane & 15, hi = lane >> 4;
  const int bxr = blockIdx.x;
  const int chunk = (bxr & 1) ? (15 - (bxr >> 1)) : (bxr >> 1);   // 0,15,1,14,...
  const int bh = blockIdx.y, b = bh >> 4, h = bh & 15, g = h >> 1;
  const int q0w = chunk * 128 + w * 32;
  const int sw = (lo & 7) << 4;

  // Q fragments (B operand = Q^T): rows q0w+qf*16+lo, d = half*32 + hi*8
  short8 qA[2][2];
#pragma unroll
  for (int qf = 0; qf < 2; ++qf)
#pragma unroll
    for (int half = 0; half < 2; ++half)
      qA[qf][half] = *(const short8*)(qkv +
          (size_t)(b * 2048 + q0w + qf * 16 + lo) * 2048 + h * 64 + half * 32 + hi * 8);

  const f32x4 vzero = {0.f, 0.f, 0.f, 0.f};
  f32x4 zacc[2][4];   // [qf][kf]: Z[q=qf*16+lo][k=kf*16+hi*4+r]
#pragma unroll
  for (int qf = 0; qf < 2; ++qf)
#pragma unroll
    for (int kf = 0; kf < 4; ++kf) zacc[qf][kf] = vzero;
  float mrun[2] = {-1e30f, -1e30f};
  float lrun[2] = {0.f, 0.f};

  const u16* kbase = qkv + (size_t)b * 2048 * 2048 + 1024 + g * 64;
  const u16* vbase = vt + (size_t)(b * 8 + g) * 64 * 2048;

  const int p0 = w * 2048 + lane * 16;
  int srow[2], scol[2];
#pragma unroll
  for (int c = 0; c < 2; ++c) {
    const int p = p0 + c * 1024;
    const int r = p >> 7, bb = p & 127;
    srow[c] = r;
    scol[c] = (bb ^ ((r & 7) << 4)) >> 1;
  }

  const int nTiles = (chunk + 1) * 2;
  u16* pw = &Pl[w][0];

  for (int it = 0; it < nTiles; ++it) {
    const int t0 = it * 64;
    __syncthreads();   // previous tile's LDS reads complete
#pragma unroll
    for (int c = 0; c < 2; ++c) {
      __builtin_amdgcn_global_load_lds(
          (const __attribute__((address_space(1))) void*)(kbase + (size_t)(t0 + srow[c]) * 2048 + scol[c]),
          (__attribute__((address_space(3))) void*)((char*)Ks + p0 + c * 1024), 16, 0, 0);
      __builtin_amdgcn_global_load_lds(
          (const __attribute__((address_space(1))) void*)(vbase + (size_t)srow[c] * 2048 + t0 + scol[c]),
          (__attribute__((address_space(3))) void*)((char*)Vs + p0 + c * 1024), 16, 0, 0);
    }
    __syncthreads();   // staging visible

    if (t0 < q0w + 32) {
      short8 kA[4][2];
#pragma unroll
      for (int nt = 0; nt < 4; ++nt)
#pragma unroll
        for (int half = 0; half < 2; ++half)
          kA[nt][half] = *(const short8*)((const char*)Ks + (nt * 16 + lo) * 128 + ((half * 64 + hi * 16) ^ sw));

#pragma unroll
      for (int qf = 0; qf < 2; ++qf) {
        f32x4 p[4];
#pragma unroll
        for (int nt = 0; nt < 4; ++nt) {
          f32x4 t = MFMA16(kA[nt][0], qA[qf][0], vzero);
          p[nt] = MFMA16(kA[nt][1], qA[qf][1], t);
        }
        const int rel = q0w + qf * 16 + lo - t0;   // q - t0
        const bool needMask = (t0 + 63 > q0w + qf * 16);
#pragma unroll
        for (int nt = 0; nt < 4; ++nt)
#pragma unroll
          for (int r = 0; r < 4; ++r) {
            float val = p[nt][r] * SCL2;
            if (needMask && (nt * 16 + hi * 4 + r > rel)) val = -1e30f;
            p[nt][r] = val;
          }
        // in-lane max tree (16 vals) + 2 cross-lane steps (across hi)
        float m0 = fmaxf(fmaxf(p[0][0], p[0][1]), fmaxf(p[0][2], p[0][3]));
        float m1 = fmaxf(fmaxf(p[1][0], p[1][1]), fmaxf(p[1][2], p[1][3]));
        float m2 = fmaxf(fmaxf(p[2][0], p[2][1]), fmaxf(p[2][2], p[2][3]));
        float m3 = fmaxf(fmaxf(p[3][0], p[3][1]), fmaxf(p[3][2], p[3][3]));
        float mx = fmaxf(fmaxf(m0, m1), fmaxf(m2, m3));
        mx = fmaxf(mx, __shfl_xor(mx, 16));
        mx = fmaxf(mx, __shfl_xor(mx, 32));
        const float nm = fmaxf(mrun[qf], mx);
        const float sc = exp2f(mrun[qf] - nm);
        mrun[qf] = nm;
#pragma unroll
        for (int nt = 0; nt < 4; ++nt)
#pragma unroll
          for (int r = 0; r < 4; ++r) p[nt][r] = exp2f(p[nt][r] - nm);
        float s0 = (p[0][0] + p[0][1]) + (p[0][2] + p[0][3]);
        float s1 = (p[1][0] + p[1][1]) + (p[1][2] + p[1][3]);
        float s2 = (p[2][0] + p[2][1]) + (p[2][2] + p[2][3]);
        float s3 = (p[3][0] + p[3][1]) + (p[3][2] + p[3][3]);
        float rs = (s0 + s1) + (s2 + s3);
        rs += __shfl_xor(rs, 16);
        rs += __shfl_xor(rs, 32);
        lrun[qf] = lrun[qf] * sc + rs;
#pragma unroll
        for (int kf = 0; kf < 4; ++kf)
#pragma unroll
          for (int r = 0; r < 4; ++r) zacc[qf][kf][r] *= sc;
        // pack P -> LDS: row q-local, cols t = nt*16 + hi*4 + {0..3}
#pragma unroll
        for (int nt = 0; nt < 4; ++nt) {
          uint2 uu;
          uu.x = (unsigned)f2bf(p[nt][0]) | ((unsigned)f2bf(p[nt][1]) << 16);
          uu.y = (unsigned)f2bf(p[nt][2]) | ((unsigned)f2bf(p[nt][3]) << 16);
          *(uint2*)((char*)pw + (qf * 16 + lo) * 144 + nt * 32 + hi * 8) = uu;
        }
      }
      asm volatile("s_waitcnt lgkmcnt(0)" ::: "memory");
      short8 pa[2][2];
#pragma unroll
      for (int qf = 0; qf < 2; ++qf)
#pragma unroll
        for (int tc = 0; tc < 2; ++tc)
          pa[qf][tc] = *(const short8*)((const char*)pw + (qf * 16 + lo) * 144 + tc * 64 + hi * 16);
#pragma unroll
      for (int kf = 0; kf < 4; ++kf) {
#pragma unroll
        for (int tc = 0; tc < 2; ++tc) {
          const short8 vf = *(const short8*)((const char*)Vs + (kf * 16 + lo) * 128 + ((tc * 64 + hi * 16) ^ sw));
          zacc[0][kf] = MFMA16(vf, pa[0][tc], zacc[0][kf]);
          zacc[1][kf] = MFMA16(vf, pa[1][tc], zacc[1][kf]);
        }
      }
    }
  }

  u16* zp = z + (size_t)(b * 2048 + q0w) * 1024 + h * 64;
#pragma unroll
  for (int qf = 0; qf < 2; ++qf) {
    const float inv = 1.f / lrun[qf];
#pragma unroll
    for (int kf = 0; kf < 4; ++kf) {
      ushort4 o;
      o.x = f2bf(zacc[qf][kf][0] * inv);
      o.y = f2bf(zacc[qf][kf][1] * inv);
      o.z = f2bf(zacc[qf][kf][2] * inv);
      o.w = f2bf(zacc[qf][kf][3] * inv);
      *(ushort4*)(zp + (size_t)(qf * 16 + lo) * 1024 + kf * 16 + hi * 4) = o;
    }
  }
}

// ---------------------------------------------------------------------------

extern "C" void kernel_launch(void* const* d_in, const int* in_sizes, int n_in,
                              void* d_out, int out_size, void* d_ws, size_t ws_size,
                              hipStream_t stream)
{
  (void)in_sizes; (void)n_in; (void)out_size; (void)ws_size;
  const float* x      = (const float*)d_in[0];
  const float* ln1_w  = (const float*)d_in[1];
  const float* ln1_b  = (const float*)d_in[2];
  const float* W_Q    = (const float*)d_in[3];
  const float* W_K    = (const float*)d_in[4];
  const float* W_V    = (const float*)d_in[5];
  const float* W_out  = (const float*)d_in[6];
  const float* b_out  = (const float*)d_in[7];
  const float* ln2_w  = (const float*)d_in[8];
  const float* ln2_b  = (const float*)d_in[9];
  const float* mlp1_w = (const float*)d_in[10];
  const float* mlp1_b = (const float*)d_in[11];
  const float* mlp2_w = (const float*)d_in[12];
  const float* mlp2_b = (const float*)d_in[13];
  float* out = (float*)d_out;

  char* ws = (char*)d_ws;
  u16*   wqkv_t = (u16*)(ws + 0);           // [2048][1024] bf16   4 MB
  u16*   wout_t = (u16*)(ws + 4194304);     // [1024][1024] bf16   2 MB
  u16*   w1     = (u16*)(ws + 6291456);     // [4096][1024] bf16   8 MB
  u16*   w2     = (u16*)(ws + 14680064);    // [1024][4096] bf16   8 MB
  u16*   normed = (u16*)(ws + 23068672);    // [4096][1024] bf16   8 MB
  float* post   = (float*)(ws + 31457280);  // [4096][1024] f32   16 MB
  u16*   qkv    = (u16*)(ws + 48234496);    // [4096][2048] bf16  16 MB
  u16*   vtb    = (u16*)(ws + 65011712);    // [16][64][2048] bf16 4 MB
  u16*   zb     = (u16*)(ws + 69206016);    // [4096][1024] bf16   8 MB
  u16*   hbuf   = (u16*)(ws + 48234496);    // [4096][4096] bf16  32 MB (reuses qkv/vt/z)

  prep_wqkv<<<dim3(64, 32), 256, 0, stream>>>(W_Q, W_K, W_V, wqkv_t);
  prep_wout<<<dim3(32, 32), 256, 0, stream>>>(W_out, wout_t);
  convert_bf16<<<4096, 256, 0, stream>>>((const float4*)mlp1_w, w1, 1048576);
  convert_bf16<<<4096, 256, 0, stream>>>((const float4*)mlp2_w, w2, 1048576);

  ln_bf16<<<4096, 256, 0, stream>>>(x, ln1_w, ln1_b, normed);
  gemm_bt<0><<<dim3(32, 16), 256, 0, stream>>>(normed, wqkv_t, qkv, nullptr, nullptr, 4096, 2048, 1024);
  vt_transpose<<<dim3(64, 2, 16), 256, 0, stream>>>(qkv, vtb);
  attn_fwd<<<dim3(16, 32), 256, 0, stream>>>(qkv, vtb, zb);
  gemm_bt<1><<<dim3(32, 8), 256, 0, stream>>>(zb, wout_t, post, b_out, x, 4096, 1024, 1024);
  ln_bf16<<<4096, 256, 0, stream>>>(post, ln2_w, ln2_b, normed);
  gemm_bt<2><<<dim3(32, 32), 256, 0, stream>>>(normed, w1, hbuf, mlp1_b, nullptr, 4096, 4096, 1024);
  gemm_bt<1><<<dim3(32, 8), 256, 0, stream>>>(hbuf, w2, out, mlp2_b, post, 4096, 1024, 4096);
}